// Round 4
// baseline (692.444 us; speedup 1.0000x reference)
//
#include <hip/hip_runtime.h>
#include <cstdint>
#include <cstddef>

typedef __bf16 bf16_t;
typedef __bf16 bf16x8 __attribute__((ext_vector_type(8)));
typedef __bf16 bf16x4 __attribute__((ext_vector_type(4)));
typedef float  f32x4  __attribute__((ext_vector_type(4)));

#define MFMA(a, b, c) __builtin_amdgcn_mfma_f32_16x16x32_bf16((a), (b), (c), 0, 0, 0)

// BS=64, S=128, DM=512, H=8, DK=DV=512, PRED=96, NF=65536

// ---------------------------------------------------------------- converts
__global__ __launch_bounds__(256) void k_convert(const float* __restrict__ in,
                                                 bf16_t* __restrict__ out, int n) {
  int i = (blockIdx.x * 256 + threadIdx.x) * 4;
  if (i < n) {
    float4 v = *(const float4*)(in + i);
    bf16x4 o;
    o[0] = (bf16_t)v.x; o[1] = (bf16_t)v.y; o[2] = (bf16_t)v.z; o[3] = (bf16_t)v.w;
    *(bf16x4*)(out + i) = o;
  }
}

// out[c][r] = (bf16) in[r][c]   (R,C multiples of 32)
__global__ __launch_bounds__(256) void k_transpose_convert(const float* __restrict__ in,
                                                           bf16_t* __restrict__ out,
                                                           int R, int C) {
  __shared__ float tile[32][33];
  int tx = threadIdx.x & 31, ty = threadIdx.x >> 5;
  int c0 = blockIdx.x * 32, r0 = blockIdx.y * 32;
#pragma unroll
  for (int j = 0; j < 4; ++j)
    tile[ty + j * 8][tx] = in[(size_t)(r0 + ty + j * 8) * C + c0 + tx];
  __syncthreads();
#pragma unroll
  for (int j = 0; j < 4; ++j)
    out[(size_t)(c0 + ty + j * 8) * R + r0 + tx] = (bf16_t)tile[tx][ty + j * 8];
}

// batched bf16 transpose: in [b][R][C] -> out [b][C][R], grid (C/32, R/32, B)
__global__ __launch_bounds__(256) void k_transpose_b16(const bf16_t* __restrict__ in,
                                                       bf16_t* __restrict__ out,
                                                       int R, int C) {
  __shared__ bf16_t tile[32][34];
  size_t base = (size_t)blockIdx.z * R * C;
  int tx = threadIdx.x & 31, ty = threadIdx.x >> 5;
  int c0 = blockIdx.x * 32, r0 = blockIdx.y * 32;
#pragma unroll
  for (int j = 0; j < 4; ++j)
    tile[ty + j * 8][tx] = in[base + (size_t)(r0 + ty + j * 8) * C + c0 + tx];
  __syncthreads();
#pragma unroll
  for (int j = 0; j < 4; ++j)
    out[base + (size_t)(c0 + ty + j * 8) * R + r0 + tx] = tile[tx][ty + j * 8];
}

// ---------------------------------------------------------------- weight products
// BMODE 0 (Bt1): out[(h*512+j)*512 + i] = sum_d Wq[i][h*512+d] * Wk[j][h*512+d]
// BMODE 1 (Bt2): out[n*4096 + h*512 + i] = sum_d Wv[i][h*512+d] * Wo[h*512+d][n]
template <int BMODE>
__global__ __launch_bounds__(256) void k_wprod(const float* __restrict__ Ap,
                                               const float* __restrict__ Bp,
                                               bf16_t* __restrict__ out,
                                               int ldA, int ldB) {
  __shared__ __align__(16) bf16_t As[128 * 68];
  __shared__ __align__(16) bf16_t Bs[128 * 68];
  const int tid = threadIdx.x, lane = tid & 63, wave = tid >> 6;
  const int wr = (wave >> 1) * 64, wc = (wave & 1) * 64;
  const int lr = lane & 15, lk = (lane >> 4) * 8, frow = (lane >> 4) * 4;
  const int m0 = blockIdx.x * 128, n0 = blockIdx.y * 128, h = blockIdx.z;
  const int sr = tid >> 3, sc = (tid & 7) * 8;
  f32x4 acc[4][4] = {};

  for (int kt = 0; kt < 512; kt += 64) {
#pragma unroll
    for (int rr = 0; rr < 4; ++rr) {
      int r = sr + 32 * rr;
      const float* ap = Ap + (size_t)(m0 + r) * ldA + h * 512 + kt + sc;
      bf16x8 av;
#pragma unroll
      for (int e = 0; e < 8; ++e) av[e] = (bf16_t)ap[e];
      *(bf16x8*)(As + r * 68 + sc) = av;
    }
    if (BMODE == 0) {
#pragma unroll
      for (int rr = 0; rr < 4; ++rr) {
        int r = sr + 32 * rr;
        const float* bp = Bp + (size_t)(n0 + r) * ldB + h * 512 + kt + sc;
        bf16x8 bv;
#pragma unroll
        for (int e = 0; e < 8; ++e) bv[e] = (bf16_t)bp[e];
        *(bf16x8*)(Bs + r * 68 + sc) = bv;
      }
    } else {
#pragma unroll
      for (int rr = 0; rr < 8; ++rr) {
        int kr = (tid >> 5) + 8 * rr;          // 0..63
        int nc = (tid & 31) * 4;               // 0..124
        const float* bp = Bp + (size_t)(h * 512 + kt + kr) * ldB + n0 + nc;
        float4 v = *(const float4*)bp;
        Bs[(nc + 0) * 68 + kr] = (bf16_t)v.x;
        Bs[(nc + 1) * 68 + kr] = (bf16_t)v.y;
        Bs[(nc + 2) * 68 + kr] = (bf16_t)v.z;
        Bs[(nc + 3) * 68 + kr] = (bf16_t)v.w;
      }
    }
    __syncthreads();
#pragma unroll
    for (int kk = 0; kk < 2; ++kk) {
      bf16x8 af[4], bfr[4];
#pragma unroll
      for (int i = 0; i < 4; ++i)
        af[i] = *(const bf16x8*)(As + (wr + i * 16 + lr) * 68 + kk * 32 + lk);
#pragma unroll
      for (int j = 0; j < 4; ++j)
        bfr[j] = *(const bf16x8*)(Bs + (wc + j * 16 + lr) * 68 + kk * 32 + lk);
#pragma unroll
      for (int i = 0; i < 4; ++i)
#pragma unroll
        for (int j = 0; j < 4; ++j)
          acc[i][j] = MFMA(af[i], bfr[j], acc[i][j]);
    }
    __syncthreads();
  }
#pragma unroll
  for (int i = 0; i < 4; ++i)
#pragma unroll
    for (int j = 0; j < 4; ++j)
#pragma unroll
      for (int q = 0; q < 4; ++q) {
        int gm = m0 + wr + i * 16 + frow + q;  // i index
        int gn = n0 + wc + j * 16 + lr;        // j (BMODE0) / n (BMODE1)
        if (BMODE == 0)
          out[(size_t)(h * 512 + gn) * 512 + gm] = (bf16_t)acc[i][j][q];
        else
          out[(size_t)gn * 4096 + h * 512 + gm] = (bf16_t)acc[i][j][q];
      }
}

// ---------------------------------------------------------------- bias helpers
__global__ __launch_bounds__(256) void k_sbias(const float* __restrict__ Wq,
                                               const float* __restrict__ bk,
                                               const float* __restrict__ Wk,
                                               const float* __restrict__ bq,
                                               float* __restrict__ W1,
                                               float* __restrict__ W2,
                                               float* __restrict__ c) {
  const int lane = threadIdx.x & 63, wave = threadIdx.x >> 6;
  const int i = blockIdx.x * 4 + wave;  // [0,512)
  for (int h = 0; h < 8; ++h) {
    float s1 = 0.f, s2 = 0.f;
    for (int d = lane; d < 512; d += 64) {
      s1 += Wq[(size_t)i * 4096 + h * 512 + d] * bk[h * 512 + d];
      s2 += Wk[(size_t)i * 4096 + h * 512 + d] * bq[h * 512 + d];
    }
#pragma unroll
    for (int o = 32; o > 0; o >>= 1) { s1 += __shfl_down(s1, o); s2 += __shfl_down(s2, o); }
    if (lane == 0) { W1[i * 8 + h] = s1; W2[i * 8 + h] = s2; }
  }
  if (blockIdx.x == 0 && wave == 0) {
    for (int h = 0; h < 8; ++h) {
      float cc = 0.f;
      for (int d = lane; d < 512; d += 64) cc += bq[h * 512 + d] * bk[h * 512 + d];
#pragma unroll
      for (int o = 32; o > 0; o >>= 1) cc += __shfl_down(cc, o);
      if (lane == 0) c[h] = cc;
    }
  }
}

// cvec[d] = sum_n bv[n]*Wo[n][d] + bo[d]
__global__ __launch_bounds__(256) void k_cvec(const float* __restrict__ bv,
                                              const float* __restrict__ Wo,
                                              const float* __restrict__ bo,
                                              float* __restrict__ cvec) {
  int d = blockIdx.x * 256 + threadIdx.x;
  float s = 0.f;
  for (int n = 0; n < 4096; ++n) s += bv[n] * Wo[(size_t)n * 512 + d];
  cvec[d] = s + bo[d];
}

// o1b = bf16(o1acc + cvec[col])
__global__ __launch_bounds__(256) void k_final(const float* __restrict__ o1acc,
                                               const float* __restrict__ cvec,
                                               bf16_t* __restrict__ o1b, int n4) {
  int i = blockIdx.x * 256 + threadIdx.x;
  if (i < n4) {
    float4 v = *(const float4*)(o1acc + i * 4);
    float4 cv = *(const float4*)(cvec + ((i * 4) & 511));
    bf16x4 o;
    o[0] = (bf16_t)(v.x + cv.x); o[1] = (bf16_t)(v.y + cv.y);
    o[2] = (bf16_t)(v.z + cv.z); o[3] = (bf16_t)(v.w + cv.w);
    *(bf16x4*)(o1b + i * 4) = o;
  }
}

// ---------------------------------------------------------------- attention core
// grid 256: bx = b*4 + h'. h = hg*4+h'. TU = [8192][2048] bf16 (in: T, out: U).
// S = T_bh @ x_b^T; S' = scl*(S + T1[s] + T2[s'] + c) + prev; P = softmax(S');
// U = P @ x_b  (overwrites T region of this block).
__global__ __launch_bounds__(256, 2) void k_attn2(const bf16_t* __restrict__ xb,
                                                  bf16_t* __restrict__ TU,
                                                  const float* __restrict__ prev,
                                                  const float* __restrict__ scale_p,
                                                  const float* __restrict__ W1,
                                                  const float* __restrict__ W2,
                                                  const float* __restrict__ cb,
                                                  int hg) {
  __shared__ __align__(16) bf16_t lds[34304];  // Ts[128*68] Xs[128*68] Pl[128*132]
  bf16_t* Ts = lds;
  bf16_t* Xs = lds + 8704;
  bf16_t* Pl = lds + 17408;
  bf16_t* Xt = lds;  // reuse Ts: [64][132] = 8448 el
  __shared__ float T1s[128], T2s[128];
  __shared__ float csh;

  const int tid = threadIdx.x, lane = tid & 63, wave = tid >> 6;
  const int lr = lane & 15, lk = (lane >> 4) * 8, frow = (lane >> 4) * 4;
  const int wrow = wave * 32;
  const int sr = tid >> 3, sc = (tid & 7) * 8;
  const int b = blockIdx.x >> 2, hp_ = blockIdx.x & 3;
  const int h = hg * 4 + hp_;
  const bf16_t* xB = xb + (size_t)b * 65536;
  bf16_t* tB = TU + (size_t)b * 128 * 2048 + hp_ * 512;

  // ---- prologue: T1s,T2s,csh
  {
    int q = tid & 127, part = tid >> 7;
    float s1 = 0.f, s2 = 0.f;
    const bf16_t* xrow = xB + (size_t)q * 512;
    for (int i = part * 256; i < part * 256 + 256; ++i) {
      float xv = (float)xrow[i];
      s1 += xv * W1[i * 8 + h];
      s2 += xv * W2[i * 8 + h];
    }
    float* scr = (float*)Pl;
    scr[tid] = s1; scr[256 + tid] = s2;
    if (tid == 0) csh = cb[h];
    __syncthreads();
    if (tid < 128) {
      T1s[tid] = scr[tid] + scr[tid + 128];
      T2s[tid] = scr[tid + 256] + scr[tid + 384];
    }
    __syncthreads();
  }

  // ---- S = T @ x^T  (K=512)
  f32x4 sacc[2][8] = {};
  for (int kt = 0; kt < 8; ++kt) {
#pragma unroll
    for (int rr = 0; rr < 4; ++rr) {
      int r = sr + 32 * rr;
      *(bf16x8*)(Ts + r * 68 + sc) = *(const bf16x8*)(tB + (size_t)r * 2048 + kt * 64 + sc);
      *(bf16x8*)(Xs + r * 68 + sc) = *(const bf16x8*)(xB + (size_t)r * 512 + kt * 64 + sc);
    }
    __syncthreads();
#pragma unroll
    for (int kk = 0; kk < 2; ++kk) {
      bf16x8 af[2], bfr[8];
#pragma unroll
      for (int i = 0; i < 2; ++i)
        af[i] = *(const bf16x8*)(Ts + (wrow + i * 16 + lr) * 68 + kk * 32 + lk);
#pragma unroll
      for (int j = 0; j < 8; ++j)
        bfr[j] = *(const bf16x8*)(Xs + (j * 16 + lr) * 68 + kk * 32 + lk);
#pragma unroll
      for (int i = 0; i < 2; ++i)
#pragma unroll
        for (int j = 0; j < 8; ++j)
          sacc[i][j] = MFMA(af[i], bfr[j], sacc[i][j]);
    }
    __syncthreads();
  }

  // ---- softmax (rows in 16-lane groups)
  const float scl = scale_p[0];
#pragma unroll
  for (int i2 = 0; i2 < 2; ++i2) {
#pragma unroll
    for (int e = 0; e < 4; ++e) {
      const int row = wrow + i2 * 16 + frow + e;
      const float* prow = prev + ((size_t)(b * 8 + h) * 128 + row) * 128;
      float mx = -3.4e38f;
#pragma unroll
      for (int j = 0; j < 8; ++j) {
        int col = j * 16 + lr;
        float v = scl * (sacc[i2][j][e] + T1s[row] + T2s[col] + csh) + prow[col];
        sacc[i2][j][e] = v;
        mx = fmaxf(mx, v);
      }
      mx = fmaxf(mx, __shfl_xor(mx, 1));
      mx = fmaxf(mx, __shfl_xor(mx, 2));
      mx = fmaxf(mx, __shfl_xor(mx, 4));
      mx = fmaxf(mx, __shfl_xor(mx, 8));
      float sum = 0.f;
#pragma unroll
      for (int j = 0; j < 8; ++j) {
        float p = __expf(sacc[i2][j][e] - mx);
        sacc[i2][j][e] = p;
        sum += p;
      }
      sum += __shfl_xor(sum, 1);
      sum += __shfl_xor(sum, 2);
      sum += __shfl_xor(sum, 4);
      sum += __shfl_xor(sum, 8);
      float inv = 1.f / sum;
#pragma unroll
      for (int j = 0; j < 8; ++j)
        Pl[row * 132 + j * 16 + lr] = (bf16_t)(sacc[i2][j][e] * inv);
    }
  }
  __syncthreads();

  // ---- U = P @ x  (K=128), chunked over i-cols (8 x 64); overwrite T region
  for (int dc = 0; dc < 8; ++dc) {
#pragma unroll
    for (int rr = 0; rr < 4; ++rr) {
      int r = sr + 32 * rr;  // s' index
      bf16x8 v8 = *(const bf16x8*)(xB + (size_t)r * 512 + dc * 64 + sc);
#pragma unroll
      for (int j = 0; j < 8; ++j) Xt[(sc + j) * 132 + r] = v8[j];
    }
    __syncthreads();
    f32x4 oacc[2][4] = {};
#pragma unroll
    for (int kk = 0; kk < 4; ++kk) {
      bf16x8 af[2], bfr[4];
#pragma unroll
      for (int i = 0; i < 2; ++i)
        af[i] = *(const bf16x8*)(Pl + (wrow + i * 16 + lr) * 132 + kk * 32 + lk);
#pragma unroll
      for (int j = 0; j < 4; ++j)
        bfr[j] = *(const bf16x8*)(Xt + (j * 16 + lr) * 132 + kk * 32 + lk);
#pragma unroll
      for (int i = 0; i < 2; ++i)
#pragma unroll
        for (int j = 0; j < 4; ++j)
          oacc[i][j] = MFMA(af[i], bfr[j], oacc[i][j]);
    }
#pragma unroll
    for (int i2 = 0; i2 < 2; ++i2)
#pragma unroll
      for (int j2 = 0; j2 < 4; ++j2)
#pragma unroll
        for (int e = 0; e < 4; ++e) {
          int row = wrow + i2 * 16 + frow + e;
          int col = dc * 64 + j2 * 16 + lr;
          tB[(size_t)row * 2048 + col] = (bf16_t)oacc[i2][j2][e];
        }
    __syncthreads();
  }
}

// ---------------------------------------------------------------- generic GEMM
// C[M][N] = A[M][K] @ Bt[N][K]^T + bias (opt relu), bf16 out.
template <int RELU>
__global__ __launch_bounds__(256) void k_gemm(const bf16_t* __restrict__ A,
                                              const bf16_t* __restrict__ Bt,
                                              const float* __restrict__ bias,
                                              bf16_t* __restrict__ C,
                                              int M, int N, int K) {
  __shared__ __align__(16) bf16_t As[128 * 68];
  __shared__ __align__(16) bf16_t Bs[128 * 68];
  const int tid = threadIdx.x, lane = tid & 63, wave = tid >> 6;
  const int wr = (wave >> 1) * 64, wc = (wave & 1) * 64;
  const int m0 = blockIdx.x * 128, n0 = blockIdx.y * 128;
  const int lr = lane & 15, lk = (lane >> 4) * 8, frow = (lane >> 4) * 4;
  const int sr = tid >> 3, sc = (tid & 7) * 8;
  f32x4 acc[4][4] = {};

  for (int kt = 0; kt < K; kt += 64) {
#pragma unroll
    for (int i = 0; i < 4; ++i) {
      int r = i * 32 + sr;
      *(bf16x8*)(As + r * 68 + sc) = *(const bf16x8*)(A + (size_t)(m0 + r) * K + kt + sc);
      *(bf16x8*)(Bs + r * 68 + sc) = *(const bf16x8*)(Bt + (size_t)(n0 + r) * K + kt + sc);
    }
    __syncthreads();
#pragma unroll
    for (int kk = 0; kk < 2; ++kk) {
      bf16x8 af[4], bfr[4];
#pragma unroll
      for (int i = 0; i < 4; ++i)
        af[i] = *(const bf16x8*)(As + (wr + i * 16 + lr) * 68 + kk * 32 + lk);
#pragma unroll
      for (int j = 0; j < 4; ++j)
        bfr[j] = *(const bf16x8*)(Bs + (wc + j * 16 + lr) * 68 + kk * 32 + lk);
#pragma unroll
      for (int i = 0; i < 4; ++i)
#pragma unroll
        for (int j = 0; j < 4; ++j)
          acc[i][j] = MFMA(af[i], bfr[j], acc[i][j]);
    }
    __syncthreads();
  }
#pragma unroll
  for (int j = 0; j < 4; ++j) {
    int gn = n0 + wc + j * 16 + lr;
    float bv = bias ? bias[gn] : 0.0f;
#pragma unroll
    for (int i = 0; i < 4; ++i) {
#pragma unroll
      for (int q = 0; q < 4; ++q) {
        int gm = m0 + wr + i * 16 + frow + q;
        float v = acc[i][j][q] + bv;
        if (RELU) v = v > 0.0f ? v : 0.0f;
        C[(size_t)gm * N + gn] = (bf16_t)v;
      }
    }
  }
}

// f32-accumulating GEMM: C[M][N] (f32) = (ADD? C : 0) + A[M][K] @ Bt[N][ldB slice]^T
template <int ADD>
__global__ __launch_bounds__(256) void k_gemm_acc(const bf16_t* __restrict__ A,
                                                  const bf16_t* __restrict__ Bt,
                                                  float* __restrict__ C,
                                                  int M, int N, int K, int ldB) {
  __shared__ __align__(16) bf16_t As[128 * 68];
  __shared__ __align__(16) bf16_t Bs[128 * 68];
  const int tid = threadIdx.x, lane = tid & 63, wave = tid >> 6;
  const int wr = (wave >> 1) * 64, wc = (wave & 1) * 64;
  const int m0 = blockIdx.x * 128, n0 = blockIdx.y * 128;
  const int lr = lane & 15, lk = (lane >> 4) * 8, frow = (lane >> 4) * 4;
  const int sr = tid >> 3, sc = (tid & 7) * 8;
  f32x4 acc[4][4] = {};

  for (int kt = 0; kt < K; kt += 64) {
#pragma unroll
    for (int i = 0; i < 4; ++i) {
      int r = i * 32 + sr;
      *(bf16x8*)(As + r * 68 + sc) = *(const bf16x8*)(A + (size_t)(m0 + r) * K + kt + sc);
      *(bf16x8*)(Bs + r * 68 + sc) = *(const bf16x8*)(Bt + (size_t)(n0 + r) * ldB + kt + sc);
    }
    __syncthreads();
#pragma unroll
    for (int kk = 0; kk < 2; ++kk) {
      bf16x8 af[4], bfr[4];
#pragma unroll
      for (int i = 0; i < 4; ++i)
        af[i] = *(const bf16x8*)(As + (wr + i * 16 + lr) * 68 + kk * 32 + lk);
#pragma unroll
      for (int j = 0; j < 4; ++j)
        bfr[j] = *(const bf16x8*)(Bs + (wc + j * 16 + lr) * 68 + kk * 32 + lk);
#pragma unroll
      for (int i = 0; i < 4; ++i)
#pragma unroll
        for (int j = 0; j < 4; ++j)
          acc[i][j] = MFMA(af[i], bfr[j], acc[i][j]);
    }
    __syncthreads();
  }
#pragma unroll
  for (int j = 0; j < 4; ++j) {
    int gn = n0 + wc + j * 16 + lr;
#pragma unroll
    for (int i = 0; i < 4; ++i) {
#pragma unroll
      for (int q = 0; q < 4; ++q) {
        int gm = m0 + wr + i * 16 + frow + q;
        size_t idx = (size_t)gm * N + gn;
        float v = acc[i][j][q];
        if (ADD) v += C[idx];
        C[idx] = v;
      }
    }
  }
}

// ---------------------------------------------------------------- head (split-K)
__global__ __launch_bounds__(256) void k_head_partial(const bf16_t* __restrict__ Z,
                                                      const bf16_t* __restrict__ WhT,
                                                      float* __restrict__ part) {
  __shared__ __align__(16) bf16_t As[64 * 68];
  __shared__ __align__(16) bf16_t Bs[96 * 68];
  const int tid = threadIdx.x, lane = tid & 63, wave = tid >> 6;
  const int wr = (wave >> 1) * 32, wc = (wave & 1) * 48;
  const int lr = lane & 15, lk = (lane >> 4) * 8, frow = (lane >> 4) * 4;
  const int k0 = blockIdx.x * 512;
  const int sr = tid >> 3, sc = (tid & 7) * 8;
  f32x4 acc[2][3] = {};
  for (int kt = 0; kt < 512; kt += 64) {
#pragma unroll
    for (int i = 0; i < 2; ++i) {
      int r = i * 32 + sr;
      *(bf16x8*)(As + r * 68 + sc) = *(const bf16x8*)(Z + (size_t)r * 65536 + k0 + kt + sc);
    }
#pragma unroll
    for (int i = 0; i < 3; ++i) {
      int r = i * 32 + sr;
      *(bf16x8*)(Bs + r * 68 + sc) = *(const bf16x8*)(WhT + (size_t)r * 65536 + k0 + kt + sc);
    }
    __syncthreads();
#pragma unroll
    for (int kk = 0; kk < 2; ++kk) {
      bf16x8 af[2], bfr[3];
#pragma unroll
      for (int i = 0; i < 2; ++i)
        af[i] = *(const bf16x8*)(As + (wr + i * 16 + lr) * 68 + kk * 32 + lk);
#pragma unroll
      for (int j = 0; j < 3; ++j)
        bfr[j] = *(const bf16x8*)(Bs + (wc + j * 16 + lr) * 68 + kk * 32 + lk);
#pragma unroll
      for (int i = 0; i < 2; ++i)
#pragma unroll
        for (int j = 0; j < 3; ++j)
          acc[i][j] = MFMA(af[i], bfr[j], acc[i][j]);
    }
    __syncthreads();
  }
#pragma unroll
  for (int i = 0; i < 2; ++i)
#pragma unroll
    for (int j = 0; j < 3; ++j)
#pragma unroll
      for (int q = 0; q < 4; ++q) {
        int m = wr + i * 16 + frow + q;
        int n = wc + j * 16 + lr;
        part[(size_t)blockIdx.x * 6144 + m * 96 + n] = acc[i][j][q];
      }
}

__global__ __launch_bounds__(256) void k_head_reduce(const float* __restrict__ part,
                                                     const float* __restrict__ bias,
                                                     float* __restrict__ out) {
  int idx = blockIdx.x * 256 + threadIdx.x;
  if (idx >= 6144) return;
  float s = bias[idx % 96];
  for (int kb = 0; kb < 128; ++kb) s += part[(size_t)kb * 6144 + idx];
  out[idx] = s;
}

__global__ void k_sentinel(float* out, int n, float val) {
  int i = blockIdx.x * 256 + threadIdx.x;
  if (i < n) out[i] = val;
}

// ---------------------------------------------------------------- launch
extern "C" void kernel_launch(void* const* d_in, const int* in_sizes, int n_in,
                              void* d_out, int out_size, void* d_ws, size_t ws_size,
                              hipStream_t stream) {
  const float* x    = (const float*)d_in[0];
  const float* prev = (const float*)d_in[1];
  const float* Wq = (const float*)d_in[2];   const float* bq = (const float*)d_in[3];
  const float* Wk = (const float*)d_in[4];   const float* bk = (const float*)d_in[5];
  const float* Wv = (const float*)d_in[6];   const float* bv = (const float*)d_in[7];
  const float* Wo = (const float*)d_in[8];   const float* bo = (const float*)d_in[9];
  const float* scale = (const float*)d_in[10];
  const float* Wi1 = (const float*)d_in[11]; const float* bi1 = (const float*)d_in[12];
  const float* Wi2 = (const float*)d_in[13]; const float* bi2 = (const float*)d_in[14];
  const float* Wt1 = (const float*)d_in[15]; const float* bt1w = (const float*)d_in[16];
  const float* Wt2 = (const float*)d_in[17]; const float* bt2w = (const float*)d_in[18];
  const float* Wh = (const float*)d_in[19];  const float* bh = (const float*)d_in[20];
  float* out = (float*)d_out;

  char* p = (char*)d_ws;
  auto carve = [&](size_t bytes) {
    char* r = p;
    p += (bytes + 255) & ~(size_t)255;
    return r;
  };
  bf16_t* xb    = (bf16_t*)carve((size_t)8192 * 512 * 2);   //  8.39 MB
  float*  o1acc = (float*)carve((size_t)8192 * 512 * 4);    // 16.78 MB
  bf16_t* o1b   = (bf16_t*)carve((size_t)8192 * 512 * 2);   //  8.39 MB
  bf16_t* bt1   = (bf16_t*)carve((size_t)4096 * 512 * 2);   //  4.19 MB
  bf16_t* bt2   = (bf16_t*)carve((size_t)512 * 4096 * 2);   //  4.19 MB
  float*  W1    = (float*)carve(512 * 8 * 4);
  float*  W2    = (float*)carve(512 * 8 * 4);
  float*  cb    = (float*)carve(8 * 4);
  float*  cvec  = (float*)carve(512 * 4);
  char*   arena = carve((size_t)8192 * 2048 * 2);           // 33.55 MB (TU)
  bf16_t* TU    = (bf16_t*)arena;
  // tail view of arena (used only AFTER attention path completes):
  char* q2 = arena;
  auto carve2 = [&](size_t bytes) {
    char* r = q2;
    q2 += (bytes + 255) & ~(size_t)255;
    return r;
  };
  bf16_t* whT  = (bf16_t*)carve2((size_t)96 * 65536 * 2);   // 12.58 MB
  bf16_t* wt1T = (bf16_t*)carve2((size_t)512 * 512 * 2);
  bf16_t* wt2T = (bf16_t*)carve2((size_t)512 * 512 * 2);
  bf16_t* wi1T = (bf16_t*)carve2((size_t)128 * 128 * 2);
  bf16_t* wi2T = (bf16_t*)carve2((size_t)128 * 128 * 2);
  float*  hp   = (float*)carve2((size_t)128 * 64 * 96 * 4); //  3.15 MB
  bf16_t* bufB = (bf16_t*)carve2((size_t)8192 * 512 * 2);   //  8.39 MB

  if ((size_t)(p - (char*)d_ws) > ws_size) {
    k_sentinel<<<24, 256, 0, stream>>>(out, 6144, (float)ws_size);
    return;
  }

  dim3 blk(256);
  // ---- prep
  k_convert<<<4096, blk, 0, stream>>>(x, xb, 8192 * 512);
  k_wprod<0><<<dim3(4, 4, 8), blk, 0, stream>>>(Wq, Wk, bt1, 4096, 4096);
  k_wprod<1><<<dim3(4, 4, 8), blk, 0, stream>>>(Wv, Wo, bt2, 4096, 512);
  k_sbias<<<128, blk, 0, stream>>>(Wq, bk, Wk, bq, W1, W2, cb);
  k_cvec<<<2, blk, 0, stream>>>(bv, Wo, bo, cvec);

  // ---- attention path, 2 head-groups
  // g=0
  k_gemm<0><<<dim3(64, 16), blk, 0, stream>>>(xb, bt1, nullptr, TU, 8192, 2048, 512);
  k_attn2<<<256, blk, 0, stream>>>(xb, TU, prev, scale, W1, W2, cb, 0);
  k_gemm_acc<0><<<dim3(64, 4), blk, 0, stream>>>(TU, bt2, o1acc, 8192, 512, 2048, 4096);
  // g=1
  k_gemm<0><<<dim3(64, 16), blk, 0, stream>>>(xb, bt1 + (size_t)2048 * 512, nullptr, TU,
                                              8192, 2048, 512);
  k_attn2<<<256, blk, 0, stream>>>(xb, TU, prev, scale, W1, W2, cb, 1);
  k_gemm_acc<1><<<dim3(64, 4), blk, 0, stream>>>(TU, bt2 + 2048, o1acc, 8192, 512, 2048, 4096);

  k_final<<<4096, blk, 0, stream>>>(o1acc, cvec, o1b, 1048576);

  // ---- tail weight converts (arena now safe to overwrite)
  k_transpose_convert<<<dim3(4, 4), blk, 0, stream>>>(Wi1, wi1T, 128, 128);
  k_transpose_convert<<<dim3(4, 4), blk, 0, stream>>>(Wi2, wi2T, 128, 128);
  k_transpose_convert<<<dim3(16, 16), blk, 0, stream>>>(Wt1, wt1T, 512, 512);
  k_transpose_convert<<<dim3(16, 16), blk, 0, stream>>>(Wt2, wt2T, 512, 512);
  k_transpose_convert<<<dim3(3, 2048), blk, 0, stream>>>(Wh, whT, 65536, 96);

  // ---- InterPatchMixing: transpose, 2 gemms, transpose back
  k_transpose_b16<<<dim3(16, 4, 64), blk, 0, stream>>>(o1b, bufB, 128, 512);
  k_gemm<1><<<dim3(256, 1), blk, 0, stream>>>(bufB, wi1T, bi1, o1b, 32768, 128, 128);
  k_gemm<0><<<dim3(256, 1), blk, 0, stream>>>(o1b, wi2T, bi2, bufB, 32768, 128, 128);
  k_transpose_b16<<<dim3(4, 16, 64), blk, 0, stream>>>(bufB, o1b, 512, 128);

  // ---- IntraPatchMixing
  k_gemm<1><<<dim3(64, 4), blk, 0, stream>>>(o1b, wt1T, bt1w, bufB, 8192, 512, 512);
  k_gemm<0><<<dim3(64, 4), blk, 0, stream>>>(bufB, wt2T, bt2w, o1b, 8192, 512, 512);

  // ---- Flatten head
  k_head_partial<<<128, blk, 0, stream>>>(o1b, whT, hp);
  k_head_reduce<<<24, blk, 0, stream>>>(hp, bh, out);
}

// Round 5
// 470.159 us; speedup vs baseline: 1.4728x; 1.4728x over previous
//
#include <hip/hip_runtime.h>
#include <cstdint>
#include <cstddef>

typedef __bf16 bf16_t;
typedef __bf16 bf16x8 __attribute__((ext_vector_type(8)));
typedef __bf16 bf16x4 __attribute__((ext_vector_type(4)));
typedef float  f32x4  __attribute__((ext_vector_type(4)));

#define MFMA(a, b, c) __builtin_amdgcn_mfma_f32_16x16x32_bf16((a), (b), (c), 0, 0, 0)

// BS=64, S=128, DM=512, H=8, PRED=96, NF=65536

// ---------------------------------------------------------------- converts
// x [8192][512] f32 -> xb bf16 (same layout) + xT [b][i][s] bf16 (per-batch transpose)
__global__ __launch_bounds__(256) void k_convert_dual(const float* __restrict__ in,
                                                      bf16_t* __restrict__ xb,
                                                      bf16_t* __restrict__ xT) {
  __shared__ bf16_t tile[32][34];
  int tx = threadIdx.x & 31, ty = threadIdx.x >> 5;
  int c0 = blockIdx.x * 32, r0 = blockIdx.y * 32;  // c over 512, r over 8192
#pragma unroll
  for (int j = 0; j < 4; ++j) {
    int r = r0 + ty + j * 8;
    bf16_t bv = (bf16_t)in[(size_t)r * 512 + c0 + tx];
    xb[(size_t)r * 512 + c0 + tx] = bv;
    tile[ty + j * 8][tx] = bv;
  }
  __syncthreads();
  int b = (r0 + tx) >> 7, s = (r0 + tx) & 127;  // b constant per block (r0 % 128 in {0,32,64,96})
#pragma unroll
  for (int j = 0; j < 4; ++j) {
    int i = c0 + ty + j * 8;
    xT[(size_t)b * 65536 + (size_t)i * 128 + s] = tile[tx][ty + j * 8];
  }
}

// out[c][r] = (bf16) in[r][c]   (R,C multiples of 32)
__global__ __launch_bounds__(256) void k_transpose_convert(const float* __restrict__ in,
                                                           bf16_t* __restrict__ out,
                                                           int R, int C) {
  __shared__ float tile[32][33];
  int tx = threadIdx.x & 31, ty = threadIdx.x >> 5;
  int c0 = blockIdx.x * 32, r0 = blockIdx.y * 32;
#pragma unroll
  for (int j = 0; j < 4; ++j)
    tile[ty + j * 8][tx] = in[(size_t)(r0 + ty + j * 8) * C + c0 + tx];
  __syncthreads();
#pragma unroll
  for (int j = 0; j < 4; ++j)
    out[(size_t)(c0 + ty + j * 8) * R + r0 + tx] = (bf16_t)tile[tx][ty + j * 8];
}

// batched bf16 transpose: in [b][R][C] -> out [b][C][R], grid (C/32, R/32, B)
__global__ __launch_bounds__(256) void k_transpose_b16(const bf16_t* __restrict__ in,
                                                       bf16_t* __restrict__ out,
                                                       int R, int C) {
  __shared__ bf16_t tile[32][34];
  size_t base = (size_t)blockIdx.z * R * C;
  int tx = threadIdx.x & 31, ty = threadIdx.x >> 5;
  int c0 = blockIdx.x * 32, r0 = blockIdx.y * 32;
#pragma unroll
  for (int j = 0; j < 4; ++j)
    tile[ty + j * 8][tx] = in[base + (size_t)(r0 + ty + j * 8) * C + c0 + tx];
  __syncthreads();
#pragma unroll
  for (int j = 0; j < 4; ++j)
    out[base + (size_t)(c0 + ty + j * 8) * R + r0 + tx] = tile[tx][ty + j * 8];
}

// ---------------------------------------------------------------- weight products
// BMODE 0 (Bt1): out[(h*512+j)*512 + i] = sum_d Wq[i][h*512+d] * Wk[j][h*512+d]
// BMODE 1 (Bt2): out[n*4096 + h*512 + i] = sum_d Wv[i][h*512+d] * Wo[h*512+d][n]
template <int BMODE>
__global__ __launch_bounds__(256) void k_wprod(const float* __restrict__ Ap,
                                               const float* __restrict__ Bp,
                                               bf16_t* __restrict__ out,
                                               int ldA, int ldB) {
  __shared__ __align__(16) bf16_t As[128 * 68];
  __shared__ __align__(16) bf16_t Bs[128 * 68];
  const int tid = threadIdx.x, lane = tid & 63, wave = tid >> 6;
  const int wr = (wave >> 1) * 64, wc = (wave & 1) * 64;
  const int lr = lane & 15, lk = (lane >> 4) * 8, frow = (lane >> 4) * 4;
  const int m0 = blockIdx.x * 128, n0 = blockIdx.y * 128, h = blockIdx.z;
  const int sr = tid >> 3, sc = (tid & 7) * 8;
  f32x4 acc[4][4] = {};

  for (int kt = 0; kt < 512; kt += 64) {
#pragma unroll
    for (int rr = 0; rr < 4; ++rr) {
      int r = sr + 32 * rr;
      const float* ap = Ap + (size_t)(m0 + r) * ldA + h * 512 + kt + sc;
      bf16x8 av;
#pragma unroll
      for (int e = 0; e < 8; ++e) av[e] = (bf16_t)ap[e];
      *(bf16x8*)(As + r * 68 + sc) = av;
    }
    if (BMODE == 0) {
#pragma unroll
      for (int rr = 0; rr < 4; ++rr) {
        int r = sr + 32 * rr;
        const float* bp = Bp + (size_t)(n0 + r) * ldB + h * 512 + kt + sc;
        bf16x8 bv;
#pragma unroll
        for (int e = 0; e < 8; ++e) bv[e] = (bf16_t)bp[e];
        *(bf16x8*)(Bs + r * 68 + sc) = bv;
      }
    } else {
#pragma unroll
      for (int rr = 0; rr < 8; ++rr) {
        int kr = (tid >> 5) + 8 * rr;          // 0..63
        int nc = (tid & 31) * 4;               // 0..124
        const float* bp = Bp + (size_t)(h * 512 + kt + kr) * ldB + n0 + nc;
        float4 v = *(const float4*)bp;
        Bs[(nc + 0) * 68 + kr] = (bf16_t)v.x;
        Bs[(nc + 1) * 68 + kr] = (bf16_t)v.y;
        Bs[(nc + 2) * 68 + kr] = (bf16_t)v.z;
        Bs[(nc + 3) * 68 + kr] = (bf16_t)v.w;
      }
    }
    __syncthreads();
#pragma unroll
    for (int kk = 0; kk < 2; ++kk) {
      bf16x8 af[4], bfr[4];
#pragma unroll
      for (int i = 0; i < 4; ++i)
        af[i] = *(const bf16x8*)(As + (wr + i * 16 + lr) * 68 + kk * 32 + lk);
#pragma unroll
      for (int j = 0; j < 4; ++j)
        bfr[j] = *(const bf16x8*)(Bs + (wc + j * 16 + lr) * 68 + kk * 32 + lk);
#pragma unroll
      for (int i = 0; i < 4; ++i)
#pragma unroll
        for (int j = 0; j < 4; ++j)
          acc[i][j] = MFMA(af[i], bfr[j], acc[i][j]);
    }
    __syncthreads();
  }
#pragma unroll
  for (int i = 0; i < 4; ++i)
#pragma unroll
    for (int j = 0; j < 4; ++j)
#pragma unroll
      for (int q = 0; q < 4; ++q) {
        int gm = m0 + wr + i * 16 + frow + q;  // i index
        int gn = n0 + wc + j * 16 + lr;        // j (BMODE0) / n (BMODE1)
        if (BMODE == 0)
          out[(size_t)(h * 512 + gn) * 512 + gm] = (bf16_t)acc[i][j][q];
        else
          out[(size_t)gn * 4096 + h * 512 + gm] = (bf16_t)acc[i][j][q];
      }
}

// ---------------------------------------------------------------- bias helpers
// W1[h*512+i] = sum_d Wq[i][h*512+d]*bk[h*512+d]; W2 with (Wk,bq); c[h]=bq.bk
__global__ __launch_bounds__(256) void k_sbias(const float* __restrict__ Wq,
                                               const float* __restrict__ bk,
                                               const float* __restrict__ Wk,
                                               const float* __restrict__ bq,
                                               float* __restrict__ W1,
                                               float* __restrict__ W2,
                                               float* __restrict__ c) {
  const int lane = threadIdx.x & 63, wave = threadIdx.x >> 6;
  const int i = blockIdx.x * 4 + wave;  // [0,512)
  for (int h = 0; h < 8; ++h) {
    float s1 = 0.f, s2 = 0.f;
    for (int d = lane; d < 512; d += 64) {
      s1 += Wq[(size_t)i * 4096 + h * 512 + d] * bk[h * 512 + d];
      s2 += Wk[(size_t)i * 4096 + h * 512 + d] * bq[h * 512 + d];
    }
#pragma unroll
    for (int o = 32; o > 0; o >>= 1) { s1 += __shfl_down(s1, o); s2 += __shfl_down(s2, o); }
    if (lane == 0) { W1[h * 512 + i] = s1; W2[h * 512 + i] = s2; }
  }
  if (blockIdx.x == 0 && wave == 0) {
    for (int h = 0; h < 8; ++h) {
      float cc = 0.f;
      for (int d = lane; d < 512; d += 64) cc += bq[h * 512 + d] * bk[h * 512 + d];
#pragma unroll
      for (int o = 32; o > 0; o >>= 1) cc += __shfl_down(cc, o);
      if (lane == 0) c[h] = cc;
    }
  }
}

// cvec = bv @ Wo + bo, 2-stage
__global__ __launch_bounds__(256) void k_cvec1(const float* __restrict__ bv,
                                               const float* __restrict__ Wo,
                                               float* __restrict__ cpart) {
  int cch = blockIdx.x, d = threadIdx.x * 2;
  float ax = 0.f, ay = 0.f;
  for (int n = cch * 128; n < cch * 128 + 128; ++n) {
    float b = bv[n];
    float2 w = *(const float2*)(Wo + (size_t)n * 512 + d);
    ax += b * w.x; ay += b * w.y;
  }
  cpart[(size_t)cch * 512 + d] = ax;
  cpart[(size_t)cch * 512 + d + 1] = ay;
}
__global__ __launch_bounds__(256) void k_cvec2(const float* __restrict__ cpart,
                                               const float* __restrict__ bo,
                                               float* __restrict__ cvec) {
  int d = blockIdx.x * 256 + threadIdx.x;
  float s = bo[d];
  for (int cch = 0; cch < 32; ++cch) s += cpart[(size_t)cch * 512 + d];
  cvec[d] = s;
}

// ---------------------------------------------------------------- attention core
// grid 512: bx -> b = bx>>3, hp = (bx>>1)&3, half = bx&1; h = hg*4+hp.
// T/U slab layout: TU[hp][8192][512]. Block handles 64 q-rows (row0 = half*64).
// S = T @ x^T; S' = scl*(S + T1[s]+T2[s']+c) + prev; P = softmax(S'); U = P @ x.
__global__ __launch_bounds__(256, 2) void k_attn3(const bf16_t* __restrict__ xb,
                                                  const bf16_t* __restrict__ xT,
                                                  bf16_t* __restrict__ TU,
                                                  const float* __restrict__ prev,
                                                  const float* __restrict__ scale_p,
                                                  const float* __restrict__ W1,
                                                  const float* __restrict__ W2,
                                                  const float* __restrict__ cb,
                                                  int hg) {
  __shared__ __align__(16) bf16_t Xs[128 * 68];    // S-phase B tiles; U-phase bounce
  __shared__ __align__(16) bf16_t Pl[64 * 132];    // P
  __shared__ __align__(16) bf16_t TsXt[64 * 132];  // S: Ts[64][68]; U: Xt[64][132]
  __shared__ float T1s[64], T2s[128];
  __shared__ float csh;

  const int tid = threadIdx.x, lane = tid & 63, wave = tid >> 6;
  const int lr = lane & 15, lk = (lane >> 4) * 8, frow = (lane >> 4) * 4;
  const int sr = tid >> 3, sc = (tid & 7) * 8;
  const int b = blockIdx.x >> 3, hp = (blockIdx.x >> 1) & 3, half = blockIdx.x & 1;
  const int h = hg * 4 + hp;
  const int row0 = half * 64;
  const bf16_t* xB = xb + (size_t)b * 65536;
  bf16_t* tB = TU + ((size_t)hp * 8192 + b * 128 + row0) * 512;

  // ---- prologue: T1s (this block's 64 rows), T2s (all 128 cols)
  {
    int sp = tid >> 1, part = tid & 1;
    const bf16_t* xrow = xB + (size_t)sp * 512 + part * 256;
    const float* w1 = W1 + h * 512 + part * 256;
    const float* w2 = W2 + h * 512 + part * 256;
    float s1 = 0.f, s2 = 0.f;
    for (int i = 0; i < 256; i += 8) {
      bf16x8 xv = *(const bf16x8*)(xrow + i);
#pragma unroll
      for (int e = 0; e < 8; ++e) {
        float f = (float)xv[e];
        s1 += f * w1[i + e];
        s2 += f * w2[i + e];
      }
    }
    float* scr = (float*)Pl;
    scr[tid] = s1; scr[256 + tid] = s2;
    if (tid == 0) csh = cb[h];
    __syncthreads();
    if (tid < 128) {
      T2s[tid] = scr[256 + 2 * tid] + scr[256 + 2 * tid + 1];
      float t1v = scr[2 * tid] + scr[2 * tid + 1];
      if (tid >= row0 && tid < row0 + 64) T1s[tid - row0] = t1v;
    }
    __syncthreads();
  }

  // ---- S = T @ x^T  (64 x 128, K=512); wave owns 16 rows
  bf16_t* Ts = TsXt;  // [64][68]
  f32x4 sacc[8] = {};
  for (int kt = 0; kt < 8; ++kt) {
#pragma unroll
    for (int rr = 0; rr < 2; ++rr) {
      int r = sr + 32 * rr;
      *(bf16x8*)(Ts + r * 68 + sc) = *(const bf16x8*)(tB + (size_t)r * 512 + kt * 64 + sc);
    }
#pragma unroll
    for (int rr = 0; rr < 4; ++rr) {
      int r = sr + 32 * rr;
      *(bf16x8*)(Xs + r * 68 + sc) = *(const bf16x8*)(xB + (size_t)r * 512 + kt * 64 + sc);
    }
    __syncthreads();
#pragma unroll
    for (int kk = 0; kk < 2; ++kk) {
      bf16x8 af = *(const bf16x8*)(Ts + (wave * 16 + lr) * 68 + kk * 32 + lk);
      bf16x8 bfr[8];
#pragma unroll
      for (int j = 0; j < 8; ++j)
        bfr[j] = *(const bf16x8*)(Xs + (j * 16 + lr) * 68 + kk * 32 + lk);
#pragma unroll
      for (int j = 0; j < 8; ++j) sacc[j] = MFMA(af, bfr[j], sacc[j]);
    }
    __syncthreads();
  }

  // ---- softmax (row lives in a 16-lane group)
  const float scl = scale_p[0];
#pragma unroll
  for (int e = 0; e < 4; ++e) {
    const int rl = wave * 16 + frow + e;
    const float* prow = prev + (((size_t)(b * 8 + h)) * 128 + row0 + rl) * 128;
    float mx = -3.4e38f;
#pragma unroll
    for (int j = 0; j < 8; ++j) {
      int col = j * 16 + lr;
      float v = scl * (sacc[j][e] + T1s[rl] + T2s[col] + csh) + prow[col];
      sacc[j][e] = v;
      mx = fmaxf(mx, v);
    }
    mx = fmaxf(mx, __shfl_xor(mx, 1));
    mx = fmaxf(mx, __shfl_xor(mx, 2));
    mx = fmaxf(mx, __shfl_xor(mx, 4));
    mx = fmaxf(mx, __shfl_xor(mx, 8));
    float sum = 0.f;
#pragma unroll
    for (int j = 0; j < 8; ++j) {
      float p = __expf(sacc[j][e] - mx);
      sacc[j][e] = p;
      sum += p;
    }
    sum += __shfl_xor(sum, 1);
    sum += __shfl_xor(sum, 2);
    sum += __shfl_xor(sum, 4);
    sum += __shfl_xor(sum, 8);
    float inv = 1.f / sum;
#pragma unroll
    for (int j = 0; j < 8; ++j)
      Pl[rl * 132 + j * 16 + lr] = (bf16_t)(sacc[j][e] * inv);
  }
  __syncthreads();

  // ---- U = P @ x (64 x 512, K=128), chunked over 8 x 64 cols; in-place over T
  bf16_t* Xt = TsXt;  // [64][132]
  const bf16_t* xTB = xT + (size_t)b * 65536;
  for (int dc = 0; dc < 8; ++dc) {
#pragma unroll
    for (int rr = 0; rr < 4; ++rr) {
      int r = (tid >> 4) + 16 * rr;
      *(bf16x8*)(Xt + r * 132 + (tid & 15) * 8) =
          *(const bf16x8*)(xTB + (size_t)(dc * 64 + r) * 128 + (tid & 15) * 8);
    }
    __syncthreads();
    f32x4 oacc[4] = {};
#pragma unroll
    for (int kk = 0; kk < 4; ++kk) {
      bf16x8 af = *(const bf16x8*)(Pl + (wave * 16 + lr) * 132 + kk * 32 + lk);
      bf16x8 bfr[4];
#pragma unroll
      for (int j = 0; j < 4; ++j)
        bfr[j] = *(const bf16x8*)(Xt + (j * 16 + lr) * 132 + kk * 32 + lk);
#pragma unroll
      for (int j = 0; j < 4; ++j) oacc[j] = MFMA(af, bfr[j], oacc[j]);
    }
    __syncthreads();
    // bounce via Xs[64][68] for vectorized global stores
#pragma unroll
    for (int j = 0; j < 4; ++j)
#pragma unroll
      for (int e = 0; e < 4; ++e)
        Xs[(wave * 16 + frow + e) * 68 + j * 16 + lr] = (bf16_t)oacc[j][e];
    __syncthreads();
#pragma unroll
    for (int rr = 0; rr < 2; ++rr) {
      int r = sr + 32 * rr;
      *(bf16x8*)(tB + (size_t)r * 512 + dc * 64 + sc) = *(const bf16x8*)(Xs + r * 68 + sc);
    }
  }
}

// ---------------------------------------------------------------- generic GEMM
// C[M][N] = A[M][K] @ Bt[N][K]^T + bias (opt relu), bf16 out.
// OUTMODE 0: row-major.  OUTMODE 2: slab store C[((gn>>9)*8192+gm)*512 + (gn&511)]
template <int OUTMODE, int RELU>
__global__ __launch_bounds__(256) void k_gemm(const bf16_t* __restrict__ A,
                                              const bf16_t* __restrict__ Bt,
                                              const float* __restrict__ bias,
                                              bf16_t* __restrict__ C,
                                              int M, int N, int K) {
  __shared__ __align__(16) bf16_t As[128 * 68];
  __shared__ __align__(16) bf16_t Bs[128 * 68];
  const int tid = threadIdx.x, lane = tid & 63, wave = tid >> 6;
  const int wr = (wave >> 1) * 64, wc = (wave & 1) * 64;
  const int m0 = blockIdx.x * 128, n0 = blockIdx.y * 128;
  const int lr = lane & 15, lk = (lane >> 4) * 8, frow = (lane >> 4) * 4;
  const int sr = tid >> 3, sc = (tid & 7) * 8;
  f32x4 acc[4][4] = {};

  for (int kt = 0; kt < K; kt += 64) {
#pragma unroll
    for (int i = 0; i < 4; ++i) {
      int r = i * 32 + sr;
      *(bf16x8*)(As + r * 68 + sc) = *(const bf16x8*)(A + (size_t)(m0 + r) * K + kt + sc);
      *(bf16x8*)(Bs + r * 68 + sc) = *(const bf16x8*)(Bt + (size_t)(n0 + r) * K + kt + sc);
    }
    __syncthreads();
#pragma unroll
    for (int kk = 0; kk < 2; ++kk) {
      bf16x8 af[4], bfr[4];
#pragma unroll
      for (int i = 0; i < 4; ++i)
        af[i] = *(const bf16x8*)(As + (wr + i * 16 + lr) * 68 + kk * 32 + lk);
#pragma unroll
      for (int j = 0; j < 4; ++j)
        bfr[j] = *(const bf16x8*)(Bs + (wc + j * 16 + lr) * 68 + kk * 32 + lk);
#pragma unroll
      for (int i = 0; i < 4; ++i)
#pragma unroll
        for (int j = 0; j < 4; ++j)
          acc[i][j] = MFMA(af[i], bfr[j], acc[i][j]);
    }
    __syncthreads();
  }
#pragma unroll
  for (int j = 0; j < 4; ++j) {
    int gn = n0 + wc + j * 16 + lr;
    float bv = bias ? bias[gn] : 0.0f;
#pragma unroll
    for (int i = 0; i < 4; ++i) {
#pragma unroll
      for (int q = 0; q < 4; ++q) {
        int gm = m0 + wr + i * 16 + frow + q;
        float v = acc[i][j][q] + bv;
        if (RELU) v = v > 0.0f ? v : 0.0f;
        if (OUTMODE == 0)
          C[(size_t)gm * N + gn] = (bf16_t)v;
        else
          C[((size_t)(gn >> 9) * 8192 + gm) * 512 + (gn & 511)] = (bf16_t)v;
      }
    }
  }
}

// GEMM2: o1 = U @ Bt2_g.  U slab layout [4][8192][512] (K=2048).
// MODE 0: o1acc (f32) = result.  MODE 1: o1b (bf16) = result + o1acc + cvec.
template <int MODE>
__global__ __launch_bounds__(256) void k_gemm2(const bf16_t* __restrict__ U,
                                               const bf16_t* __restrict__ bt2,
                                               float* __restrict__ o1acc,
                                               const float* __restrict__ cvec,
                                               bf16_t* __restrict__ o1b, int g) {
  __shared__ __align__(16) bf16_t As[128 * 68];
  __shared__ __align__(16) bf16_t Bs[128 * 68];
  const int tid = threadIdx.x, lane = tid & 63, wave = tid >> 6;
  const int wr = (wave >> 1) * 64, wc = (wave & 1) * 64;
  const int m0 = blockIdx.x * 128, n0 = blockIdx.y * 128;
  const int lr = lane & 15, lk = (lane >> 4) * 8, frow = (lane >> 4) * 4;
  const int sr = tid >> 3, sc = (tid & 7) * 8;
  f32x4 acc[4][4] = {};

  for (int kt = 0; kt < 2048; kt += 64) {
    const int slab = kt >> 9, off = kt & 511;
#pragma unroll
    for (int i = 0; i < 4; ++i) {
      int r = i * 32 + sr;
      *(bf16x8*)(As + r * 68 + sc) =
          *(const bf16x8*)(U + ((size_t)slab * 8192 + m0 + r) * 512 + off + sc);
      *(bf16x8*)(Bs + r * 68 + sc) =
          *(const bf16x8*)(bt2 + (size_t)(n0 + r) * 4096 + g * 2048 + kt + sc);
    }
    __syncthreads();
#pragma unroll
    for (int kk = 0; kk < 2; ++kk) {
      bf16x8 af[4], bfr[4];
#pragma unroll
      for (int i = 0; i < 4; ++i)
        af[i] = *(const bf16x8*)(As + (wr + i * 16 + lr) * 68 + kk * 32 + lk);
#pragma unroll
      for (int j = 0; j < 4; ++j)
        bfr[j] = *(const bf16x8*)(Bs + (wc + j * 16 + lr) * 68 + kk * 32 + lk);
#pragma unroll
      for (int i = 0; i < 4; ++i)
#pragma unroll
        for (int j = 0; j < 4; ++j)
          acc[i][j] = MFMA(af[i], bfr[j], acc[i][j]);
    }
    __syncthreads();
  }
#pragma unroll
  for (int j = 0; j < 4; ++j) {
    int gn = n0 + wc + j * 16 + lr;
#pragma unroll
    for (int i = 0; i < 4; ++i) {
#pragma unroll
      for (int q = 0; q < 4; ++q) {
        int gm = m0 + wr + i * 16 + frow + q;
        size_t idx = (size_t)gm * 512 + gn;
        if (MODE == 0)
          o1acc[idx] = acc[i][j][q];
        else
          o1b[idx] = (bf16_t)(acc[i][j][q] + o1acc[idx] + cvec[gn]);
      }
    }
  }
}

// ---------------------------------------------------------------- head (split-K)
__global__ __launch_bounds__(256) void k_head_partial(const bf16_t* __restrict__ Z,
                                                      const bf16_t* __restrict__ WhT,
                                                      float* __restrict__ part) {
  __shared__ __align__(16) bf16_t As[64 * 68];
  __shared__ __align__(16) bf16_t Bs[96 * 68];
  const int tid = threadIdx.x, lane = tid & 63, wave = tid >> 6;
  const int wr = (wave >> 1) * 32, wc = (wave & 1) * 48;
  const int lr = lane & 15, lk = (lane >> 4) * 8, frow = (lane >> 4) * 4;
  const int k0 = blockIdx.x * 512;
  const int sr = tid >> 3, sc = (tid & 7) * 8;
  f32x4 acc[2][3] = {};
  for (int kt = 0; kt < 512; kt += 64) {
#pragma unroll
    for (int i = 0; i < 2; ++i) {
      int r = i * 32 + sr;
      *(bf16x8*)(As + r * 68 + sc) = *(const bf16x8*)(Z + (size_t)r * 65536 + k0 + kt + sc);
    }
#pragma unroll
    for (int i = 0; i < 3; ++i) {
      int r = i * 32 + sr;
      *(bf16x8*)(Bs + r * 68 + sc) = *(const bf16x8*)(WhT + (size_t)r * 65536 + k0 + kt + sc);
    }
    __syncthreads();
#pragma unroll
    for (int kk = 0; kk < 2; ++kk) {
      bf16x8 af[2], bfr[3];
#pragma unroll
      for (int i = 0; i < 2; ++i)
        af[i] = *(const bf16x8*)(As + (wr + i * 16 + lr) * 68 + kk * 32 + lk);
#pragma unroll
      for (int j = 0; j < 3; ++j)
        bfr[j] = *(const bf16x8*)(Bs + (wc + j * 16 + lr) * 68 + kk * 32 + lk);
#pragma unroll
      for (int i = 0; i < 2; ++i)
#pragma unroll
        for (int j = 0; j < 3; ++j)
          acc[i][j] = MFMA(af[i], bfr[j], acc[i][j]);
    }
    __syncthreads();
  }
#pragma unroll
  for (int i = 0; i < 2; ++i)
#pragma unroll
    for (int j = 0; j < 3; ++j)
#pragma unroll
      for (int q = 0; q < 4; ++q) {
        int m = wr + i * 16 + frow + q;
        int n = wc + j * 16 + lr;
        part[(size_t)blockIdx.x * 6144 + m * 96 + n] = acc[i][j][q];
      }
}

__global__ __launch_bounds__(256) void k_head_reduce(const float* __restrict__ part,
                                                     const float* __restrict__ bias,
                                                     float* __restrict__ out) {
  int idx = blockIdx.x * 256 + threadIdx.x;
  if (idx >= 6144) return;
  float s = bias[idx % 96];
  for (int kb = 0; kb < 128; ++kb) s += part[(size_t)kb * 6144 + idx];
  out[idx] = s;
}

__global__ void k_sentinel(float* out, int n, float val) {
  int i = blockIdx.x * 256 + threadIdx.x;
  if (i < n) out[i] = val;
}

// ---------------------------------------------------------------- launch
extern "C" void kernel_launch(void* const* d_in, const int* in_sizes, int n_in,
                              void* d_out, int out_size, void* d_ws, size_t ws_size,
                              hipStream_t stream) {
  const float* x    = (const float*)d_in[0];
  const float* prev = (const float*)d_in[1];
  const float* Wq = (const float*)d_in[2];   const float* bq = (const float*)d_in[3];
  const float* Wk = (const float*)d_in[4];   const float* bk = (const float*)d_in[5];
  const float* Wv = (const float*)d_in[6];   const float* bv = (const float*)d_in[7];
  const float* Wo = (const float*)d_in[8];   const float* bo = (const float*)d_in[9];
  const float* scale = (const float*)d_in[10];
  const float* Wi1 = (const float*)d_in[11]; const float* bi1 = (const float*)d_in[12];
  const float* Wi2 = (const float*)d_in[13]; const float* bi2 = (const float*)d_in[14];
  const float* Wt1 = (const float*)d_in[15]; const float* bt1w = (const float*)d_in[16];
  const float* Wt2 = (const float*)d_in[17]; const float* bt2w = (const float*)d_in[18];
  const float* Wh = (const float*)d_in[19];  const float* bh = (const float*)d_in[20];
  float* out = (float*)d_out;

  char* p = (char*)d_ws;
  auto carve = [&](size_t bytes) {
    char* r = p;
    p += (bytes + 255) & ~(size_t)255;
    return r;
  };
  bf16_t* xb    = (bf16_t*)carve((size_t)8192 * 512 * 2);   //  8.39 MB
  bf16_t* xTo1b = (bf16_t*)carve((size_t)8192 * 512 * 2);   //  8.39 MB (xT, later o1b)
  float*  o1acc = (float*)carve((size_t)8192 * 512 * 4);    // 16.78 MB
  bf16_t* bt1   = (bf16_t*)carve((size_t)4096 * 512 * 2);   //  4.19 MB
  bf16_t* bt2   = (bf16_t*)carve((size_t)512 * 4096 * 2);   //  4.19 MB
  float*  W1    = (float*)carve(8 * 512 * 4);
  float*  W2    = (float*)carve(8 * 512 * 4);
  float*  cb    = (float*)carve(8 * 4);
  float*  cvec  = (float*)carve(512 * 4);
  char*   arena = carve((size_t)8192 * 2048 * 2);           // 33.55 MB (TU slabs)
  bf16_t* TU    = (bf16_t*)arena;
  float*  cpart = (float*)arena;  // transient (consumed before GEMM1)
  bf16_t* xT    = xTo1b;
  bf16_t* o1b   = xTo1b;
  // tail view of arena (used only AFTER attention path completes):
  char* q2 = arena;
  auto carve2 = [&](size_t bytes) {
    char* r = q2;
    q2 += (bytes + 255) & ~(size_t)255;
    return r;
  };
  bf16_t* whT  = (bf16_t*)carve2((size_t)96 * 65536 * 2);   // 12.58 MB
  bf16_t* wt1T = (bf16_t*)carve2((size_t)512 * 512 * 2);
  bf16_t* wt2T = (bf16_t*)carve2((size_t)512 * 512 * 2);
  bf16_t* wi1T = (bf16_t*)carve2((size_t)128 * 128 * 2);
  bf16_t* wi2T = (bf16_t*)carve2((size_t)128 * 128 * 2);
  float*  hp   = (float*)carve2((size_t)128 * 64 * 96 * 4); //  3.15 MB
  bf16_t* bufB = (bf16_t*)carve2((size_t)8192 * 512 * 2);   //  8.39 MB

  if ((size_t)(p - (char*)d_ws) > ws_size) {
    k_sentinel<<<24, 256, 0, stream>>>(out, 6144, (float)ws_size);
    return;
  }

  dim3 blk(256);
  // ---- prep
  k_cvec1<<<32, blk, 0, stream>>>(bv, Wo, cpart);
  k_cvec2<<<2, blk, 0, stream>>>(cpart, bo, cvec);
  k_convert_dual<<<dim3(16, 256), blk, 0, stream>>>(x, xb, xT);
  k_wprod<0><<<dim3(4, 4, 8), blk, 0, stream>>>(Wq, Wk, bt1, 4096, 4096);
  k_wprod<1><<<dim3(4, 4, 8), blk, 0, stream>>>(Wv, Wo, bt2, 4096, 512);
  k_sbias<<<128, blk, 0, stream>>>(Wq, bk, Wk, bq, W1, W2, cb);

  // ---- attention path, 2 head-groups
  // g=0
  k_gemm<2, 0><<<dim3(64, 16), blk, 0, stream>>>(xb, bt1, nullptr, TU, 8192, 2048, 512);
  k_attn3<<<512, blk, 0, stream>>>(xb, xT, TU, prev, scale, W1, W2, cb, 0);
  k_gemm2<0><<<dim3(64, 4), blk, 0, stream>>>(TU, bt2, o1acc, cvec, o1b, 0);
  // g=1
  k_gemm<2, 0><<<dim3(64, 16), blk, 0, stream>>>(xb, bt1 + (size_t)2048 * 512, nullptr, TU,
                                                 8192, 2048, 512);
  k_attn3<<<512, blk, 0, stream>>>(xb, xT, TU, prev, scale, W1, W2, cb, 1);
  k_gemm2<1><<<dim3(64, 4), blk, 0, stream>>>(TU, bt2, o1acc, cvec, o1b, 1);

  // ---- tail weight converts (arena now safe to overwrite)
  k_transpose_convert<<<dim3(4, 4), blk, 0, stream>>>(Wi1, wi1T, 128, 128);
  k_transpose_convert<<<dim3(4, 4), blk, 0, stream>>>(Wi2, wi2T, 128, 128);
  k_transpose_convert<<<dim3(16, 16), blk, 0, stream>>>(Wt1, wt1T, 512, 512);
  k_transpose_convert<<<dim3(16, 16), blk, 0, stream>>>(Wt2, wt2T, 512, 512);
  k_transpose_convert<<<dim3(3, 2048), blk, 0, stream>>>(Wh, whT, 65536, 96);

  // ---- InterPatchMixing: transpose, 2 gemms, transpose back
  k_transpose_b16<<<dim3(16, 4, 64), blk, 0, stream>>>(o1b, bufB, 128, 512);
  k_gemm<0, 1><<<dim3(256, 1), blk, 0, stream>>>(bufB, wi1T, bi1, o1b, 32768, 128, 128);
  k_gemm<0, 0><<<dim3(256, 1), blk, 0, stream>>>(o1b, wi2T, bi2, bufB, 32768, 128, 128);
  k_transpose_b16<<<dim3(4, 16, 64), blk, 0, stream>>>(bufB, o1b, 512, 128);

  // ---- IntraPatchMixing
  k_gemm<0, 1><<<dim3(64, 4), blk, 0, stream>>>(o1b, wt1T, bt1w, bufB, 8192, 512, 512);
  k_gemm<0, 0><<<dim3(64, 4), blk, 0, stream>>>(bufB, wt2T, bt2w, o1b, 8192, 512, 512);

  // ---- Flatten head
  k_head_partial<<<128, blk, 0, stream>>>(o1b, whT, hp);
  k_head_reduce<<<24, blk, 0, stream>>>(hp, bh, out);
}